// Round 1
// baseline (161.348 us; speedup 1.0000x reference)
//
#include <hip/hip_runtime.h>
#include <hip/hip_bf16.h>

#define B_   8
#define TQ_  100
#define TS_  100
#define E_   512
#define D_   512
#define K_   1024
#define M_   (B_*TQ_*TS_)   // 80000

#define MT   64             // M-tile per block
#define BK   64             // K per staged step
#define NTHREADS 512        // 8 waves

typedef __attribute__((ext_vector_type(4))) float f32x4;
typedef __attribute__((ext_vector_type(8))) short bf16x8;

__device__ __forceinline__ short f2bf(float f) {
  __hip_bfloat16 h = __float2bfloat16(f);   // round-to-nearest
  return *reinterpret_cast<short*>(&h);
}

__device__ __forceinline__ float fast_tanh(float x) {
  // 1 - 2/(e^{2x}+1): no NaN at either extreme (x>>0 -> 1, x<<0 -> -1)
  float e = __expf(2.0f * x);
  return 1.0f - 2.0f / (e + 1.0f);
}

// ---- prep: W1 [K=1024][D=512] f32  ->  W1t bf16 [D=512][K=1024] ----
__global__ void prep_w1(const float* __restrict__ W1, short* __restrict__ W1t) {
  int idx = blockIdx.x * 256 + threadIdx.x;   // over K_*D_
  int k = idx >> 9;          // /512
  int n = idx & (D_ - 1);
  W1t[(size_t)n * K_ + k] = f2bf(W1[idx]);
}

// ---- kernel 1: scores[m] = sum_n w2[n] * tanh( cat[m,:] . W1[:,n] + b1[n] ) ----
__launch_bounds__(NTHREADS, 4)
__global__ void scores_kernel(const float* __restrict__ src,
                              const float* __restrict__ tgt,
                              const short* __restrict__ W1t,
                              const float* __restrict__ b1,
                              const float* __restrict__ w2,
                              float* __restrict__ scores) {
  // LDS: A tile (64 rows x 64 k, bf16, 128B rows) + B tile (512 n x 64 k)
  __shared__ __align__(16) char Alds[MT * 128];
  __shared__ __align__(16) char Blds[D_ * 128];
  __shared__ float s_sc[MT];

  const int tid  = threadIdx.x;
  const int wave = tid >> 6;
  const int lane = tid & 63;
  const int lr   = lane & 15;   // fragment row/col index
  const int lg   = lane >> 4;   // k-octet group
  const int m0   = blockIdx.x * MT;

  f32x4 acc[4][4];
  #pragma unroll
  for (int i = 0; i < 4; i++)
    #pragma unroll
    for (int j = 0; j < 4; j++)
      acc[i][j] = (f32x4){0.f, 0.f, 0.f, 0.f};

  const int ar = tid >> 3;         // 0..63 (row for A-stage / base n for B-stage)
  const int ac = (tid & 7) * 8;    // k sub-offset 0,8,...,56

  for (int k0 = 0; k0 < K_; k0 += BK) {
    // ---- stage A: rows m0..m0+63, k0..k0+63 (fp32 -> bf16) ----
    {
      const float* Ap = ((k0 < E_) ? src : tgt)
                        + (size_t)(m0 + ar) * E_ + (k0 & (E_ - 1)) + ac;
      f32x4 v0 = *reinterpret_cast<const f32x4*>(Ap);
      f32x4 v1 = *reinterpret_cast<const f32x4*>(Ap + 4);
      bf16x8 w;
      w[0] = f2bf(v0[0]); w[1] = f2bf(v0[1]); w[2] = f2bf(v0[2]); w[3] = f2bf(v0[3]);
      w[4] = f2bf(v1[0]); w[5] = f2bf(v1[1]); w[6] = f2bf(v1[2]); w[7] = f2bf(v1[3]);
      *reinterpret_cast<bf16x8*>(Alds + ar * 128 + ((ac * 2) ^ ((ar & 7) << 4))) = w;
    }
    // ---- stage B: W1t rows n=0..511, k0..k0+63 (bf16 passthrough) ----
    #pragma unroll
    for (int i = 0; i < 8; i++) {
      int n = ar + i * 64;
      bf16x8 v = *reinterpret_cast<const bf16x8*>(W1t + (size_t)n * K_ + k0 + ac);
      *reinterpret_cast<bf16x8*>(Blds + n * 128 + ((ac * 2) ^ ((n & 7) << 4))) = v;
    }
    __syncthreads();

    // ---- MFMA: wave owns cols [wave*64, wave*64+64) ----
    #pragma unroll
    for (int kk = 0; kk < 2; kk++) {
      const int kb = kk * 64 + lg * 16;   // byte offset of this lane's k-octet
      bf16x8 a[4], b[4];
      #pragma unroll
      for (int mi = 0; mi < 4; mi++) {
        int row = mi * 16 + lr;
        a[mi] = *reinterpret_cast<const bf16x8*>(
                    Alds + row * 128 + (kb ^ ((row & 7) << 4)));
      }
      #pragma unroll
      for (int ni = 0; ni < 4; ni++) {
        int n = wave * 64 + ni * 16 + lr;
        b[ni] = *reinterpret_cast<const bf16x8*>(
                    Blds + n * 128 + (kb ^ ((n & 7) << 4)));
      }
      #pragma unroll
      for (int mi = 0; mi < 4; mi++)
        #pragma unroll
        for (int ni = 0; ni < 4; ni++)
          acc[mi][ni] = __builtin_amdgcn_mfma_f32_16x16x32_bf16(
                            a[mi], b[ni], acc[mi][ni], 0, 0, 0);
    }
    __syncthreads();
  }

  // ---- epilogue: scores[m] = sum_n w2[n]*tanh(h[m,n]+b1[n]) ----
  if (tid < MT) s_sc[tid] = 0.0f;
  __syncthreads();

  float b1v[4], w2v[4];
  #pragma unroll
  for (int ni = 0; ni < 4; ni++) {
    int n = wave * 64 + ni * 16 + lr;
    b1v[ni] = b1[n];
    w2v[ni] = w2[n];
  }
  #pragma unroll
  for (int mi = 0; mi < 4; mi++) {
    #pragma unroll
    for (int r = 0; r < 4; r++) {
      // D layout: row = lg*4 + r (within 16), col = lr
      float p = 0.0f;
      #pragma unroll
      for (int ni = 0; ni < 4; ni++)
        p += fast_tanh(acc[mi][ni][r] + b1v[ni]) * w2v[ni];
      // reduce over the 16 col-lanes (same lg group)
      p += __shfl_xor(p, 1);
      p += __shfl_xor(p, 2);
      p += __shfl_xor(p, 4);
      p += __shfl_xor(p, 8);
      if (lr == 0) atomicAdd(&s_sc[mi * 16 + lg * 4 + r], p);
    }
  }
  __syncthreads();
  if (tid < MT) scores[m0 + tid] = s_sc[tid];
}

// ---- kernel 2: mask, softmax over s, weights out, weighted sum over src ----
__global__ void softmax_wsum(const float* __restrict__ src,
                             const float* __restrict__ mask,
                             const float* __restrict__ scores,
                             float* __restrict__ out) {
  const int row = blockIdx.x;     // b*TQ+q, 0..799
  const int tid = threadIdx.x;    // 512 threads
  __shared__ float s_e[TS_];

  float v = 0.0f;
  if (tid < TS_) {
    v = scores[row * TS_ + tid] * mask[row * TS_ + tid];
    s_e[tid] = v;
  }
  __syncthreads();
  float mx = -3.0e38f;
  for (int s = 0; s < TS_; s++) mx = fmaxf(mx, s_e[s]);   // LDS broadcast
  __syncthreads();
  if (tid < TS_) s_e[tid] = __expf(v - mx);
  __syncthreads();
  float sum = 0.0f;
  for (int s = 0; s < TS_; s++) sum += s_e[s];
  const float inv = 1.0f / sum;

  float* out_attn = out;                          // [800][512]
  float* out_w    = out + (size_t)B_ * TQ_ * E_;  // [800][100]
  if (tid < TS_) out_w[row * TS_ + tid] = s_e[tid] * inv;

  const float* sp = src + (size_t)row * TS_ * E_ + tid;  // thread owns dim e=tid
  float acc = 0.0f;
  #pragma unroll 4
  for (int s = 0; s < TS_; s++) acc = fmaf(s_e[s], sp[(size_t)s * E_], acc);
  out_attn[row * E_ + tid] = acc * inv;
}

extern "C" void kernel_launch(void* const* d_in, const int* in_sizes, int n_in,
                              void* d_out, int out_size, void* d_ws, size_t ws_size,
                              hipStream_t stream) {
  const float* src  = (const float*)d_in[0];
  const float* tgt  = (const float*)d_in[1];
  const float* mask = (const float*)d_in[2];
  const float* W1   = (const float*)d_in[3];
  const float* b1   = (const float*)d_in[4];
  const float* w2   = (const float*)d_in[5];

  short* W1t    = (short*)d_ws;                               // 512*1024 bf16 = 1 MB
  float* scores = (float*)((char*)d_ws + (size_t)D_ * K_ * 2); // 80000 f32

  float* out = (float*)d_out;

  hipLaunchKernelGGL(prep_w1, dim3((K_ * D_) / 256), dim3(256), 0, stream, W1, W1t);
  hipLaunchKernelGGL(scores_kernel, dim3(M_ / MT), dim3(NTHREADS), 0, stream,
                     src, tgt, W1t, b1, w2, scores);
  hipLaunchKernelGGL(softmax_wsum, dim3(B_ * TQ_), dim3(512), 0, stream,
                     src, mask, scores, out);
}